// Round 10
// baseline (227.087 us; speedup 1.0000x reference)
//
#include <hip/hip_runtime.h>
#include <math.h>

static __device__ __forceinline__ float lrelu(float x){ return x > 0.f ? x : 0.01f * x; }

// 4-accumulator dot products (ILP-4 per output; breaks the serial fmaf chain)
static __device__ __forceinline__ float dot128(const float* __restrict__ wrow,
                                               const float* __restrict__ xrow, float bias)
{
  const float4* wr = (const float4*)wrow;
  float ax = bias, ay = 0.f, az = 0.f, aw = 0.f;
  #pragma unroll
  for (int kk = 0; kk < 32; ++kk) {
    float4 w = wr[kk];
    float4 x = *(const float4*)&xrow[kk * 4];
    ax = fmaf(x.x, w.x, ax); ay = fmaf(x.y, w.y, ay);
    az = fmaf(x.z, w.z, az); aw = fmaf(x.w, w.w, aw);
  }
  return (ax + ay) + (az + aw);
}
static __device__ __forceinline__ float dot256(const float* __restrict__ wrow,
                                               const float* __restrict__ xrow, float bias)
{
  const float4* wr = (const float4*)wrow;
  float ax = bias, ay = 0.f, az = 0.f, aw = 0.f;
  #pragma unroll
  for (int kk = 0; kk < 64; ++kk) {
    float4 w = wr[kk];
    float4 x = *(const float4*)&xrow[kk * 4];
    ax = fmaf(x.x, w.x, ax); ay = fmaf(x.y, w.y, ay);
    az = fmaf(x.z, w.z, az); aw = fmaf(x.w, w.w, aw);
  }
  return (ax + ay) + (az + aw);
}

// ---- workspace layout (float offsets) ----
#define OFF_XE    196608
#define OFF_XA    294912
#define OFF_QKVE  393216
#define OFF_QKVA  688128
#define OFF_AOP   983040    // 4 splits * 768*128
#define OFF_DEN   1376256   // 4 splits * 768*4
#define OFF_AOA   1388544   // 15*96*128
#define OFF_QVE   1572864
#define OFF_QVA   1573632
#define WS_FLOATS 1575072

// ---- output layout (fp32 elems) ----
#define OUT_POL 0
#define OUT_QV  24576
#define OUT_EO  25344

#define SCALE_ATTN 0.17677669529663689f  // 1/sqrt(32)

// ================================================================
// K12ab: front end, split pipelines (768 blocks) + ILP-4 dots.
// Blocks 0..383   (A): rows -> eo -> x_e -> qkv_e
// Blocks 384..767 (B): rows -> actor -> pol -> ea -> x_a -> qkv_a
// ================================================================
__global__ __launch_bounds__(256) void k12ab_front(
    const float* __restrict__ obs,
    const float* __restrict__ aw1, const float* __restrict__ ab1,
    const float* __restrict__ aw2, const float* __restrict__ ab2,
    const float* __restrict__ aw3, const float* __restrict__ ab3,
    const float* __restrict__ eow, const float* __restrict__ eob,
    const float* __restrict__ eaw, const float* __restrict__ eab,
    const float* __restrict__ riw, const float* __restrict__ rib,
    const float* __restrict__ miw, const float* __restrict__ mib,
    float* __restrict__ out, float* __restrict__ ws)
{
  __shared__ float obs_s[2][128];
  __shared__ float h256[2][256];
  __shared__ float bufA[2][128];
  __shared__ float bufB[2][128];
  __shared__ float bufC[2][128];
  __shared__ float pol[2][32];
  const int t  = threadIdx.x;
  const int bx = blockIdx.x;
  const bool isA = (bx < 384);
  const int r0 = (isA ? bx : bx - 384) * 2;

  { int r = t >> 7, k = t & 127;
    obs_s[r][k] = obs[(r0 + r) * 128 + k]; }
  __syncthreads();

  if (isA) {
    // ---------- A: e-pipeline ----------
    const int o = t & 127, r = t >> 7;
    { // eo
      float a = dot128(eow + o * 128, obs_s[r], eob[o]);
      bufA[r][o] = a;
      out[OUT_EO + (r0 + r) * 128 + o] = a;
    }
    __syncthreads();
    { // x_e
      float a = fmaxf(dot128(riw + o * 128, bufA[r], rib[o]), 0.f);
      bufB[r][o] = a;
      ws[OFF_XE + (r0 + r) * 128 + o] = a;
    }
    __syncthreads();
    { // qkv_e
      float* qout = ws + OFF_QKVE + (size_t)r0 * 384;
      #pragma unroll
      for (int p3 = 0; p3 < 3; ++p3) {
        const int oo = p3 * 128 + o;
        qout[(size_t)r * 384 + oo] = dot128(miw + oo * 128, bufB[r], mib[oo]);
      }
    }
  } else {
    // ---------- B: actor + a-pipeline ----------
    { // layer1: 256 outs, both rows per thread (ILP-8)
      const int o = t;
      const float* wrow = aw1 + o * 128;
      float a0 = dot128(wrow, obs_s[0], ab1[o]);
      float a1 = dot128(wrow, obs_s[1], ab1[o]);
      h256[0][o] = lrelu(a0); h256[1][o] = lrelu(a1);
    }
    __syncthreads();
    { // layer2
      const int o = t & 127, r = t >> 7;
      bufA[r][o] = lrelu(dot256(aw2 + o * 256, h256[r], ab2[o]));
    }
    __syncthreads();
    if (t < 64) { // layer3 + GELU
      const int o = t & 31, r = t >> 5;
      float a = dot128(aw3 + o * 128, bufA[r], ab3[o]);
      float g = 0.5f * a * (1.f + erff(a * 0.70710678118654752f));
      pol[r][o] = g;
      out[OUT_POL + (r0 + r) * 32 + o] = g;
    }
    __syncthreads();
    { // ea = [obs, pol] @ eaw^T + eab  (chain split 4 ways)
      const int o = t & 127, r = t >> 7;
      const float4* wr = (const float4*)(eaw + o * 160);
      float ax = eab[o], ay = 0.f, az = 0.f, aw = 0.f;
      #pragma unroll
      for (int kk = 0; kk < 32; ++kk) {
        float4 w = wr[kk];
        float4 x = *(const float4*)&obs_s[r][kk * 4];
        ax = fmaf(x.x, w.x, ax); ay = fmaf(x.y, w.y, ay);
        az = fmaf(x.z, w.z, az); aw = fmaf(x.w, w.w, aw);
      }
      #pragma unroll
      for (int kk = 32; kk < 40; ++kk) {
        float4 w = wr[kk];
        float4 x = *(const float4*)&pol[r][kk * 4 - 128];
        ax = fmaf(x.x, w.x, ax); ay = fmaf(x.y, w.y, ay);
        az = fmaf(x.z, w.z, az); aw = fmaf(x.w, w.w, aw);
      }
      bufB[r][o] = (ax + ay) + (az + aw);
    }
    __syncthreads();
    { // x_a
      const int o = t & 127, r = t >> 7;
      float a = fmaxf(dot128(riw + o * 128, bufB[r], rib[o]), 0.f);
      bufC[r][o] = a;
      ws[OFF_XA + (r0 + r) * 128 + o] = a;
    }
    __syncthreads();
    { // qkv_a
      const int o = t & 127, r = t >> 7;
      float* qout = ws + OFF_QKVA + (size_t)r0 * 384;
      #pragma unroll
      for (int p3 = 0; p3 < 3; ++p3) {
        const int oo = p3 * 128 + o;
        qout[(size_t)r * 384 + oo] = dot128(miw + oo * 128, bufC[r], mib[oo]);
      }
    }
  }
}

// ================================================================
// K356: fused attention (e-flash 768 blocks + a-slices 120 blocks).
// PV loops use per-tile component partials (ILP-8).
// ================================================================
__global__ __launch_bounds__(256) void k356_attn(float* __restrict__ ws)
{
  __shared__ __align__(16) union {
    struct { float Qs[16 * 36]; float KsT[32 * 68]; float VsT[32 * 68]; float Ss[16 * 68]; } e;
    struct { float Qb[48 * 33]; float Ka[96 * 33]; float Va[96 * 36]; float Ss[48 * 97]; float rinv[48]; } a;
  } su;
  const int t  = threadIdx.x;
  const int bx = blockIdx.x;

  if (bx < 768) {
    const int l0 = (bx % 48) * 16, h = (bx / 48) & 3, sp = bx / 192;
    const float* qkve = ws + OFF_QKVE;

    for (int f = t; f < 512; f += 256)
      su.e.Qs[(f >> 5) * 36 + (f & 31)] = qkve[(size_t)(l0 + (f >> 5)) * 384 + h * 32 + (f & 31)];
    __syncthreads();

    const int l = t >> 4, j = t & 15, c0 = j * 4;
    float q[32];
    #pragma unroll
    for (int dd = 0; dd < 8; ++dd) {
      float4 qq = *(const float4*)&su.e.Qs[l * 36 + dd * 4];
      q[dd*4+0] = qq.x; q[dd*4+1] = qq.y; q[dd*4+2] = qq.z; q[dd*4+3] = qq.w;
    }
    float o0 = 0.f, o1 = 0.f, dsum = 0.f;

    for (int mt = sp * 3; mt < sp * 3 + 3; ++mt) {
      const int m0 = mt * 64;
      __syncthreads();
      for (int f = t; f < 2048; f += 256) {
        int i = f >> 5, d = f & 31;
        const float* src = qkve + (size_t)(m0 + i) * 384 + h * 32 + d;
        su.e.KsT[d * 68 + i] = src[128];
        su.e.VsT[d * 68 + i] = src[256];
      }
      __syncthreads();

      float s0 = 0.f, s1 = 0.f, s2 = 0.f, s3 = 0.f;
      #pragma unroll
      for (int d = 0; d < 32; ++d) {
        float4 kk = *(const float4*)&su.e.KsT[d * 68 + c0];
        s0 = fmaf(q[d], kk.x, s0); s1 = fmaf(q[d], kk.y, s1);
        s2 = fmaf(q[d], kk.z, s2); s3 = fmaf(q[d], kk.w, s3);
      }
      s0 = expf(s0 * SCALE_ATTN); s1 = expf(s1 * SCALE_ATTN);
      s2 = expf(s2 * SCALE_ATTN); s3 = expf(s3 * SCALE_ATTN);
      float4 sv; sv.x = s0; sv.y = s1; sv.z = s2; sv.w = s3;
      *(float4*)&su.e.Ss[l * 68 + c0] = sv;
      float psum = (s0 + s1) + (s2 + s3);
      psum += __shfl_xor(psum, 1); psum += __shfl_xor(psum, 2);
      psum += __shfl_xor(psum, 4); psum += __shfl_xor(psum, 8);
      dsum += psum;

      // PV with per-tile component partials (8 independent chains)
      float t0x=0.f,t0y=0.f,t0z=0.f,t0w=0.f, t1x=0.f,t1y=0.f,t1z=0.f,t1w=0.f;
      #pragma unroll
      for (int k4 = 0; k4 < 16; ++k4) {
        float4 p  = *(const float4*)&su.e.Ss[l * 68 + k4 * 4];
        float4 va = *(const float4*)&su.e.VsT[j * 68 + k4 * 4];
        float4 vb = *(const float4*)&su.e.VsT[(j + 16) * 68 + k4 * 4];
        t0x = fmaf(p.x, va.x, t0x); t0y = fmaf(p.y, va.y, t0y);
        t0z = fmaf(p.z, va.z, t0z); t0w = fmaf(p.w, va.w, t0w);
        t1x = fmaf(p.x, vb.x, t1x); t1y = fmaf(p.y, vb.y, t1y);
        t1z = fmaf(p.z, vb.z, t1z); t1w = fmaf(p.w, vb.w, t1w);
      }
      o0 += (t0x + t0y) + (t0z + t0w);
      o1 += (t1x + t1y) + (t1z + t1w);
    }

    float* aop = ws + OFF_AOP + (size_t)sp * 98304;
    aop[(size_t)(l0 + l) * 128 + h * 32 + j]      = o0;
    aop[(size_t)(l0 + l) * 128 + h * 32 + j + 16] = o1;
    if (j == 0) ws[OFF_DEN + sp * 3072 + (l0 + l) * 4 + h] = dsum;
  } else {
    const int z  = bx - 768;
    const int j1 = z >> 3;
    const int h  = (z & 7) >> 1, rb = z & 1;
    const int jj = j1 + 1;
    const float* qkva = ws + OFF_QKVA;

    for (int f = t; f < 3072; f += 256) {
      int ml = f >> 5, d = f & 31;
      int bp = ml >> 1, spar = ml & 1;
      int ag = spar ? jj : (jj - 1);
      const float* src = qkva + (size_t)(bp * 16 + ag) * 384 + h * 32 + d;
      su.a.Ka[ml * 33 + d] = src[128];
      su.a.Va[ml * 36 + d] = src[256];
    }
    for (int f = t; f < 1536; f += 256) {
      int ql = f >> 5, d = f & 31;
      int Lb = rb * 48 + ql;
      int b = Lb >> 1, s = Lb & 1;
      int ag = s ? jj : (jj - 1);
      su.a.Qb[ql * 33 + d] = qkva[(size_t)(b * 16 + ag) * 384 + h * 32 + d];
    }
    __syncthreads();

    {
      const int tl = (t >> 4) * 3, tm = (t & 15) * 6;
      float acc[3][6] = {{0.f}};
      #pragma unroll
      for (int d = 0; d < 32; ++d) {
        float qv[3], kv[6];
        #pragma unroll
        for (int r = 0; r < 3; ++r) qv[r] = su.a.Qb[(tl + r) * 33 + d];
        #pragma unroll
        for (int c = 0; c < 6; ++c) kv[c] = su.a.Ka[(tm + c) * 33 + d];
        #pragma unroll
        for (int r = 0; r < 3; ++r)
          #pragma unroll
          for (int c = 0; c < 6; ++c) acc[r][c] = fmaf(qv[r], kv[c], acc[r][c]);
      }
      const float wj = (float)jj, wnj = (float)(16 - jj);
      float rs[3] = {0.f, 0.f, 0.f};
      #pragma unroll
      for (int r = 0; r < 3; ++r)
        #pragma unroll
        for (int c = 0; c < 6; ++c) {
          float w = ((tm + c) & 1) ? wj : wnj;
          float p = w * expf(acc[r][c] * SCALE_ATTN);
          su.a.Ss[(tl + r) * 97 + tm + c] = p;
          rs[r] += p;
        }
      #pragma unroll
      for (int r = 0; r < 3; ++r) {
        rs[r] += __shfl_xor(rs[r], 1); rs[r] += __shfl_xor(rs[r], 2);
        rs[r] += __shfl_xor(rs[r], 4); rs[r] += __shfl_xor(rs[r], 8);
      }
      if ((t & 15) == 0) {
        su.a.rinv[tl + 0] = 1.f / rs[0];
        su.a.rinv[tl + 1] = 1.f / rs[1];
        su.a.rinv[tl + 2] = 1.f / rs[2];
      }
    }
    __syncthreads();

    if (t < 192) {
      const int l0 = (t >> 3) * 2, d0 = (t & 7) * 4;
      float a0x=0.f,a0y=0.f,a0z=0.f,a0w=0.f, a1x=0.f,a1y=0.f,a1z=0.f,a1w=0.f;
      for (int m = 0; m < 96; ++m) {
        float p0 = su.a.Ss[l0 * 97 + m], p1 = su.a.Ss[(l0 + 1) * 97 + m];
        float4 v = *(const float4*)&su.a.Va[m * 36 + d0];
        a0x = fmaf(p0, v.x, a0x); a0y = fmaf(p0, v.y, a0y);
        a0z = fmaf(p0, v.z, a0z); a0w = fmaf(p0, v.w, a0w);
        a1x = fmaf(p1, v.x, a1x); a1y = fmaf(p1, v.y, a1y);
        a1z = fmaf(p1, v.z, a1z); a1w = fmaf(p1, v.w, a1w);
      }
      const float s0 = su.a.rinv[l0], s1 = su.a.rinv[l0 + 1];
      float* ao = ws + OFF_AOA + (size_t)(j1 * 96 + rb * 48 + l0) * 128 + h * 32 + d0;
      float4 o0; o0.x = a0x * s0; o0.y = a0y * s0; o0.z = a0z * s0; o0.w = a0w * s0;
      float4 o1; o1.x = a1x * s1; o1.y = a1y * s1; o1.z = a1z * s1; o1.w = a1w * s1;
      *(float4*)ao = o0;
      *(float4*)(ao + 128) = o1;
    }
  }
}

// ================================================================
// K7: epilogue, 2 ctx rows per 128-thread block, ILP-8 dots. grid=1104.
// ================================================================
__global__ __launch_bounds__(128) void k7_epilogue(
    const float* __restrict__ mow, const float* __restrict__ mob,
    const float* __restrict__ roww, const float* __restrict__ robb,
    const float* __restrict__ qw,  const float* __restrict__ qb,
    float* __restrict__ ws)
{
  __shared__ float ao_s[2][128];
  __shared__ float t1[2][128];
  __shared__ float red2[2][2];
  const int t  = threadIdx.x;
  const int bx = blockIdx.x;
  const bool is_e = (bx < 384);
  const int r0 = is_e ? bx * 2 : (bx - 384) * 2;

  int x1off[2];
  if (is_e) {
    for (int f = t; f < 256; f += 128) {
      int i = f >> 7, c = f & 127;
      int r = r0 + i, h = c >> 5;
      float num = ws[OFF_AOP + 0*98304 + (size_t)r*128 + c]
                + ws[OFF_AOP + 1*98304 + (size_t)r*128 + c]
                + ws[OFF_AOP + 2*98304 + (size_t)r*128 + c]
                + ws[OFF_AOP + 3*98304 + (size_t)r*128 + c];
      float den = ws[OFF_DEN + 0*3072 + r*4 + h]
                + ws[OFF_DEN + 1*3072 + r*4 + h]
                + ws[OFF_DEN + 2*3072 + r*4 + h]
                + ws[OFF_DEN + 3*3072 + r*4 + h];
      ao_s[i][c] = num / den;
    }
    x1off[0] = OFF_XE + r0 * 128;
    x1off[1] = OFF_XE + (r0 + 1) * 128;
  } else {
    for (int f = t; f < 256; f += 128) {
      int i = f >> 7, c = f & 127;
      ao_s[i][c] = ws[OFF_AOA + (size_t)(r0 + i) * 128 + c];
    }
    #pragma unroll
    for (int i = 0; i < 2; ++i) {
      int rr = r0 + i;
      int jx = rr / 96, l96 = rr % 96;
      int b = l96 >> 1, s = l96 & 1;
      int ag = s ? (jx + 1) : jx;
      x1off[i] = OFF_XA + (b * 16 + ag) * 128;
    }
  }
  __syncthreads();

  { // out_proj + residual (2 rows x ILP-4)
    const int o = t;
    const float* wrow = mow + o * 128;
    t1[0][o] = dot128(wrow, ao_s[0], mob[o]) + ws[x1off[0] + o];
    t1[1][o] = dot128(wrow, ao_s[1], mob[o]) + ws[x1off[1] + o];
  }
  __syncthreads();

  float c0, c1;
  {
    const int o = t;
    const float* wrow = roww + o * 128;
    c0 = fmaxf(dot128(wrow, t1[0], robb[o]), 0.f);
    c1 = fmaxf(dot128(wrow, t1[1], robb[o]), 0.f);
  }

  const float qwt = qw[t];
  {
    float v = qwt * c0;
    v += __shfl_down(v, 32); v += __shfl_down(v, 16); v += __shfl_down(v, 8);
    v += __shfl_down(v, 4);  v += __shfl_down(v, 2);  v += __shfl_down(v, 1);
    if ((t & 63) == 0) red2[0][t >> 6] = v;
    float u = qwt * c1;
    u += __shfl_down(u, 32); u += __shfl_down(u, 16); u += __shfl_down(u, 8);
    u += __shfl_down(u, 4);  u += __shfl_down(u, 2);  u += __shfl_down(u, 1);
    if ((t & 63) == 0) red2[1][t >> 6] = u;
  }
  __syncthreads();
  if (t < 2) {
    float qv = red2[t][0] + red2[t][1] + qb[0];
    int r = r0 + t;
    if (is_e) ws[OFF_QVE + r] = qv;
    else      ws[OFF_QVA + r] = qv;
  }
}

// ================================================================
// K8: q_values[b,i] = qv_e[b,i] + sum_j qv_a
// ================================================================
__global__ __launch_bounds__(256) void k8_final(const float* __restrict__ ws, float* __restrict__ out)
{
  const int idx = blockIdx.x * 256 + threadIdx.x;
  if (idx >= 768) return;
  const int b = idx >> 4, i = idx & 15;
  float acc = ws[OFF_QVE + idx];
  const float* qva = ws + OFF_QVA;
  #pragma unroll
  for (int j = 1; j <= 15; ++j) {
    int s = (i >= j) ? 0 : 1;
    acc += qva[(j - 1) * 96 + b * 2 + s];
  }
  out[OUT_QV + idx] = acc;
}

// ================================================================
extern "C" void kernel_launch(void* const* d_in, const int* in_sizes, int n_in,
                              void* d_out, int out_size, void* d_ws, size_t ws_size,
                              hipStream_t stream)
{
  (void)in_sizes; (void)n_in; (void)out_size;
  if (ws_size < (size_t)WS_FLOATS * 4) return;

  const float* obs = (const float*)d_in[0];
  const float* aw1 = (const float*)d_in[1];
  const float* ab1 = (const float*)d_in[2];
  const float* aw2 = (const float*)d_in[3];
  const float* ab2 = (const float*)d_in[4];
  const float* aw3 = (const float*)d_in[5];
  const float* ab3 = (const float*)d_in[6];
  const float* eow = (const float*)d_in[7];
  const float* eob = (const float*)d_in[8];
  const float* eaw = (const float*)d_in[9];
  const float* eab = (const float*)d_in[10];
  const float* riw = (const float*)d_in[11];
  const float* rib = (const float*)d_in[12];
  const float* roww= (const float*)d_in[13];
  const float* robb= (const float*)d_in[14];
  const float* miw = (const float*)d_in[15];
  const float* mib = (const float*)d_in[16];
  const float* mow = (const float*)d_in[17];
  const float* mob = (const float*)d_in[18];
  const float* qw  = (const float*)d_in[19];
  const float* qb  = (const float*)d_in[20];

  float* out = (float*)d_out;
  float* ws  = (float*)d_ws;

  k12ab_front<<<dim3(768), dim3(256), 0, stream>>>(obs, aw1, ab1, aw2, ab2, aw3, ab3,
                                                   eow, eob, eaw, eab, riw, rib, miw, mib,
                                                   out, ws);
  k356_attn<<<dim3(888), dim3(256), 0, stream>>>(ws);
  k7_epilogue<<<dim3(1104), dim3(128), 0, stream>>>(mow, mob, roww, robb, qw, qb, ws);
  k8_final<<<dim3(3), dim3(256), 0, stream>>>(ws, out);
}

// Round 11
// 196.659 us; speedup vs baseline: 1.1547x; 1.1547x over previous
//
#include <hip/hip_runtime.h>
#include <math.h>

static __device__ __forceinline__ float lrelu(float x){ return x > 0.f ? x : 0.01f * x; }

// ---- workspace layout (float offsets) ----
#define OFF_XE    196608
#define OFF_XA    294912
#define OFF_QKVE  393216
#define OFF_QKVA  688128
#define OFF_AOP   983040    // 4 splits * 768*128
#define OFF_DEN   1376256   // 4 splits * 768*4
#define OFF_AOA   1388544   // 15*96*128
#define OFF_QVE   1572864
#define OFF_QVA   1573632
#define OFF_T1    1575072   // 2208*128 t1 rows
#define WS_FLOATS 1857696

// ---- output layout (fp32 elems) ----
#define OUT_POL 0
#define OUT_QV  24576
#define OUT_EO  25344

#define SCALE_ATTN 0.17677669529663689f  // 1/sqrt(32)

// ================================================================
// K12: fused front end (round-8 version: measured 57 us — best of the
// three structures tried; fused phases keep all 4 waves on the same
// weight set so L1 serves 3 of 4 waves).
// ================================================================
__global__ __launch_bounds__(256) void k12_front(
    const float* __restrict__ obs,
    const float* __restrict__ aw1, const float* __restrict__ ab1,
    const float* __restrict__ aw2, const float* __restrict__ ab2,
    const float* __restrict__ aw3, const float* __restrict__ ab3,
    const float* __restrict__ eow, const float* __restrict__ eob,
    const float* __restrict__ eaw, const float* __restrict__ eab,
    const float* __restrict__ riw, const float* __restrict__ rib,
    const float* __restrict__ miw, const float* __restrict__ mib,
    float* __restrict__ out, float* __restrict__ ws)
{
  __shared__ float obs_s[2][128];
  __shared__ float h1[2][256];
  __shared__ float h2[2][128];
  __shared__ float pol[2][32];
  __shared__ float eo_s[2][128];
  __shared__ float ea_s[2][128];
  __shared__ float xx[2][2][128];
  const int t  = threadIdx.x;
  const int r0 = blockIdx.x * 2;

  { int r = t >> 7, k = t & 127;
    obs_s[r][k] = obs[(r0 + r) * 128 + k]; }
  __syncthreads();

  { // layer1
    const int o = t;
    float a0 = ab1[o]; float a1 = a0;
    const float4* wr = (const float4*)(aw1 + o * 128);
    #pragma unroll 8
    for (int kk = 0; kk < 32; ++kk) {
      float4 w  = wr[kk];
      float4 x0 = *(const float4*)&obs_s[0][kk * 4];
      float4 x1 = *(const float4*)&obs_s[1][kk * 4];
      a0 = fmaf(x0.x, w.x, a0); a0 = fmaf(x0.y, w.y, a0);
      a0 = fmaf(x0.z, w.z, a0); a0 = fmaf(x0.w, w.w, a0);
      a1 = fmaf(x1.x, w.x, a1); a1 = fmaf(x1.y, w.y, a1);
      a1 = fmaf(x1.z, w.z, a1); a1 = fmaf(x1.w, w.w, a1);
    }
    h1[0][o] = lrelu(a0); h1[1][o] = lrelu(a1);
  }
  __syncthreads();

  if (t < 128) { // layer2
    const int o = t;
    float a0 = ab2[o]; float a1 = a0;
    const float4* wr = (const float4*)(aw2 + o * 256);
    #pragma unroll 8
    for (int kk = 0; kk < 64; ++kk) {
      float4 w  = wr[kk];
      float4 x0 = *(const float4*)&h1[0][kk * 4];
      float4 x1 = *(const float4*)&h1[1][kk * 4];
      a0 = fmaf(x0.x, w.x, a0); a0 = fmaf(x0.y, w.y, a0);
      a0 = fmaf(x0.z, w.z, a0); a0 = fmaf(x0.w, w.w, a0);
      a1 = fmaf(x1.x, w.x, a1); a1 = fmaf(x1.y, w.y, a1);
      a1 = fmaf(x1.z, w.z, a1); a1 = fmaf(x1.w, w.w, a1);
    }
    h2[0][o] = lrelu(a0); h2[1][o] = lrelu(a1);
  }
  __syncthreads();

  if (t < 64) { // layer3 + exact GELU -> policy
    const int o = t & 31, r = t >> 5;
    float a = ab3[o];
    const float4* wr = (const float4*)(aw3 + o * 128);
    #pragma unroll 8
    for (int kk = 0; kk < 32; ++kk) {
      float4 w = wr[kk];
      float4 x = *(const float4*)&h2[r][kk * 4];
      a = fmaf(x.x, w.x, a); a = fmaf(x.y, w.y, a);
      a = fmaf(x.z, w.z, a); a = fmaf(x.w, w.w, a);
    }
    float g = 0.5f * a * (1.f + erff(a * 0.70710678118654752f));
    pol[r][o] = g;
    out[OUT_POL + (r0 + r) * 32 + o] = g;
  }
  __syncthreads();

  if (t < 128) { // eo
    const int o = t;
    float a0 = eob[o]; float a1 = a0;
    const float4* wr = (const float4*)(eow + o * 128);
    #pragma unroll 8
    for (int kk = 0; kk < 32; ++kk) {
      float4 w  = wr[kk];
      float4 x0 = *(const float4*)&obs_s[0][kk * 4];
      float4 x1 = *(const float4*)&obs_s[1][kk * 4];
      a0 = fmaf(x0.x, w.x, a0); a0 = fmaf(x0.y, w.y, a0);
      a0 = fmaf(x0.z, w.z, a0); a0 = fmaf(x0.w, w.w, a0);
      a1 = fmaf(x1.x, w.x, a1); a1 = fmaf(x1.y, w.y, a1);
      a1 = fmaf(x1.z, w.z, a1); a1 = fmaf(x1.w, w.w, a1);
    }
    eo_s[0][o] = a0; eo_s[1][o] = a1;
    out[OUT_EO + (r0 + 0) * 128 + o] = a0;
    out[OUT_EO + (r0 + 1) * 128 + o] = a1;
  } else {       // ea
    const int o = t - 128;
    float a0 = eab[o]; float a1 = a0;
    const float4* wr = (const float4*)(eaw + o * 160);
    #pragma unroll 8
    for (int kk = 0; kk < 32; ++kk) {
      float4 w  = wr[kk];
      float4 x0 = *(const float4*)&obs_s[0][kk * 4];
      float4 x1 = *(const float4*)&obs_s[1][kk * 4];
      a0 = fmaf(x0.x, w.x, a0); a0 = fmaf(x0.y, w.y, a0);
      a0 = fmaf(x0.z, w.z, a0); a0 = fmaf(x0.w, w.w, a0);
      a1 = fmaf(x1.x, w.x, a1); a1 = fmaf(x1.y, w.y, a1);
      a1 = fmaf(x1.z, w.z, a1); a1 = fmaf(x1.w, w.w, a1);
    }
    #pragma unroll
    for (int kk = 32; kk < 40; ++kk) {
      float4 w  = wr[kk];
      float4 p0 = *(const float4*)&pol[0][kk * 4 - 128];
      float4 p1 = *(const float4*)&pol[1][kk * 4 - 128];
      a0 = fmaf(p0.x, w.x, a0); a0 = fmaf(p0.y, w.y, a0);
      a0 = fmaf(p0.z, w.z, a0); a0 = fmaf(p0.w, w.w, a0);
      a1 = fmaf(p1.x, w.x, a1); a1 = fmaf(p1.y, w.y, a1);
      a1 = fmaf(p1.z, w.z, a1); a1 = fmaf(p1.w, w.w, a1);
    }
    ea_s[0][o] = a0; ea_s[1][o] = a1;
  }
  __syncthreads();

  { // X phase
    const int o = t & 127, v = t >> 7;
    const float (*src)[128] = v ? ea_s : eo_s;
    float a0 = rib[o]; float a1 = a0;
    const float4* wr = (const float4*)(riw + o * 128);
    #pragma unroll 8
    for (int kk = 0; kk < 32; ++kk) {
      float4 w  = wr[kk];
      float4 x0 = *(const float4*)&src[0][kk * 4];
      float4 x1 = *(const float4*)&src[1][kk * 4];
      a0 = fmaf(x0.x, w.x, a0); a0 = fmaf(x0.y, w.y, a0);
      a0 = fmaf(x0.z, w.z, a0); a0 = fmaf(x0.w, w.w, a0);
      a1 = fmaf(x1.x, w.x, a1); a1 = fmaf(x1.y, w.y, a1);
      a1 = fmaf(x1.z, w.z, a1); a1 = fmaf(x1.w, w.w, a1);
    }
    a0 = fmaxf(a0, 0.f); a1 = fmaxf(a1, 0.f);
    xx[v][0][o] = a0; xx[v][1][o] = a1;
    float* xout = ws + (v ? OFF_XA : OFF_XE) + r0 * 128;
    xout[o] = a0; xout[128 + o] = a1;
  }
  __syncthreads();

  { // QKV phase
    const int o128 = t & 127, v = t >> 7;
    float* qout = ws + (v ? OFF_QKVA : OFF_QKVE) + (size_t)r0 * 384;
    #pragma unroll
    for (int p3 = 0; p3 < 3; ++p3) {
      const int o = p3 * 128 + o128;
      float a0 = mib[o]; float a1 = a0;
      const float4* wr = (const float4*)(miw + o * 128);
      #pragma unroll 8
      for (int kk = 0; kk < 32; ++kk) {
        float4 w  = wr[kk];
        float4 x0 = *(const float4*)&xx[v][0][kk * 4];
        float4 x1 = *(const float4*)&xx[v][1][kk * 4];
        a0 = fmaf(x0.x, w.x, a0); a0 = fmaf(x0.y, w.y, a0);
        a0 = fmaf(x0.z, w.z, a0); a0 = fmaf(x0.w, w.w, a0);
        a1 = fmaf(x1.x, w.x, a1); a1 = fmaf(x1.y, w.y, a1);
        a1 = fmaf(x1.z, w.z, a1); a1 = fmaf(x1.w, w.w, a1);
      }
      qout[o] = a0; qout[384 + o] = a1;
    }
  }
}

// ================================================================
// K356: fused attention (unchanged from round 10).
// ================================================================
__global__ __launch_bounds__(256) void k356_attn(float* __restrict__ ws)
{
  __shared__ __align__(16) union {
    struct { float Qs[16 * 36]; float KsT[32 * 68]; float VsT[32 * 68]; float Ss[16 * 68]; } e;
    struct { float Qb[48 * 33]; float Ka[96 * 33]; float Va[96 * 36]; float Ss[48 * 97]; float rinv[48]; } a;
  } su;
  const int t  = threadIdx.x;
  const int bx = blockIdx.x;

  if (bx < 768) {
    const int l0 = (bx % 48) * 16, h = (bx / 48) & 3, sp = bx / 192;
    const float* qkve = ws + OFF_QKVE;

    for (int f = t; f < 512; f += 256)
      su.e.Qs[(f >> 5) * 36 + (f & 31)] = qkve[(size_t)(l0 + (f >> 5)) * 384 + h * 32 + (f & 31)];
    __syncthreads();

    const int l = t >> 4, j = t & 15, c0 = j * 4;
    float q[32];
    #pragma unroll
    for (int dd = 0; dd < 8; ++dd) {
      float4 qq = *(const float4*)&su.e.Qs[l * 36 + dd * 4];
      q[dd*4+0] = qq.x; q[dd*4+1] = qq.y; q[dd*4+2] = qq.z; q[dd*4+3] = qq.w;
    }
    float o0 = 0.f, o1 = 0.f, dsum = 0.f;

    for (int mt = sp * 3; mt < sp * 3 + 3; ++mt) {
      const int m0 = mt * 64;
      __syncthreads();
      for (int f = t; f < 2048; f += 256) {
        int i = f >> 5, d = f & 31;
        const float* src = qkve + (size_t)(m0 + i) * 384 + h * 32 + d;
        su.e.KsT[d * 68 + i] = src[128];
        su.e.VsT[d * 68 + i] = src[256];
      }
      __syncthreads();

      float s0 = 0.f, s1 = 0.f, s2 = 0.f, s3 = 0.f;
      #pragma unroll
      for (int d = 0; d < 32; ++d) {
        float4 kk = *(const float4*)&su.e.KsT[d * 68 + c0];
        s0 = fmaf(q[d], kk.x, s0); s1 = fmaf(q[d], kk.y, s1);
        s2 = fmaf(q[d], kk.z, s2); s3 = fmaf(q[d], kk.w, s3);
      }
      s0 = expf(s0 * SCALE_ATTN); s1 = expf(s1 * SCALE_ATTN);
      s2 = expf(s2 * SCALE_ATTN); s3 = expf(s3 * SCALE_ATTN);
      float4 sv; sv.x = s0; sv.y = s1; sv.z = s2; sv.w = s3;
      *(float4*)&su.e.Ss[l * 68 + c0] = sv;
      float psum = (s0 + s1) + (s2 + s3);
      psum += __shfl_xor(psum, 1); psum += __shfl_xor(psum, 2);
      psum += __shfl_xor(psum, 4); psum += __shfl_xor(psum, 8);
      dsum += psum;

      float t0x=0.f,t0y=0.f,t0z=0.f,t0w=0.f, t1x=0.f,t1y=0.f,t1z=0.f,t1w=0.f;
      #pragma unroll
      for (int k4 = 0; k4 < 16; ++k4) {
        float4 p  = *(const float4*)&su.e.Ss[l * 68 + k4 * 4];
        float4 va = *(const float4*)&su.e.VsT[j * 68 + k4 * 4];
        float4 vb = *(const float4*)&su.e.VsT[(j + 16) * 68 + k4 * 4];
        t0x = fmaf(p.x, va.x, t0x); t0y = fmaf(p.y, va.y, t0y);
        t0z = fmaf(p.z, va.z, t0z); t0w = fmaf(p.w, va.w, t0w);
        t1x = fmaf(p.x, vb.x, t1x); t1y = fmaf(p.y, vb.y, t1y);
        t1z = fmaf(p.z, vb.z, t1z); t1w = fmaf(p.w, vb.w, t1w);
      }
      o0 += (t0x + t0y) + (t0z + t0w);
      o1 += (t1x + t1y) + (t1z + t1w);
    }

    float* aop = ws + OFF_AOP + (size_t)sp * 98304;
    aop[(size_t)(l0 + l) * 128 + h * 32 + j]      = o0;
    aop[(size_t)(l0 + l) * 128 + h * 32 + j + 16] = o1;
    if (j == 0) ws[OFF_DEN + sp * 3072 + (l0 + l) * 4 + h] = dsum;
  } else {
    const int z  = bx - 768;
    const int j1 = z >> 3;
    const int h  = (z & 7) >> 1, rb = z & 1;
    const int jj = j1 + 1;
    const float* qkva = ws + OFF_QKVA;

    for (int f = t; f < 3072; f += 256) {
      int ml = f >> 5, d = f & 31;
      int bp = ml >> 1, spar = ml & 1;
      int ag = spar ? jj : (jj - 1);
      const float* src = qkva + (size_t)(bp * 16 + ag) * 384 + h * 32 + d;
      su.a.Ka[ml * 33 + d] = src[128];
      su.a.Va[ml * 36 + d] = src[256];
    }
    for (int f = t; f < 1536; f += 256) {
      int ql = f >> 5, d = f & 31;
      int Lb = rb * 48 + ql;
      int b = Lb >> 1, s = Lb & 1;
      int ag = s ? jj : (jj - 1);
      su.a.Qb[ql * 33 + d] = qkva[(size_t)(b * 16 + ag) * 384 + h * 32 + d];
    }
    __syncthreads();

    {
      const int tl = (t >> 4) * 3, tm = (t & 15) * 6;
      float acc[3][6] = {{0.f}};
      #pragma unroll
      for (int d = 0; d < 32; ++d) {
        float qv[3], kv[6];
        #pragma unroll
        for (int r = 0; r < 3; ++r) qv[r] = su.a.Qb[(tl + r) * 33 + d];
        #pragma unroll
        for (int c = 0; c < 6; ++c) kv[c] = su.a.Ka[(tm + c) * 33 + d];
        #pragma unroll
        for (int r = 0; r < 3; ++r)
          #pragma unroll
          for (int c = 0; c < 6; ++c) acc[r][c] = fmaf(qv[r], kv[c], acc[r][c]);
      }
      const float wj = (float)jj, wnj = (float)(16 - jj);
      float rs[3] = {0.f, 0.f, 0.f};
      #pragma unroll
      for (int r = 0; r < 3; ++r)
        #pragma unroll
        for (int c = 0; c < 6; ++c) {
          float w = ((tm + c) & 1) ? wj : wnj;
          float p = w * expf(acc[r][c] * SCALE_ATTN);
          su.a.Ss[(tl + r) * 97 + tm + c] = p;
          rs[r] += p;
        }
      #pragma unroll
      for (int r = 0; r < 3; ++r) {
        rs[r] += __shfl_xor(rs[r], 1); rs[r] += __shfl_xor(rs[r], 2);
        rs[r] += __shfl_xor(rs[r], 4); rs[r] += __shfl_xor(rs[r], 8);
      }
      if ((t & 15) == 0) {
        su.a.rinv[tl + 0] = 1.f / rs[0];
        su.a.rinv[tl + 1] = 1.f / rs[1];
        su.a.rinv[tl + 2] = 1.f / rs[2];
      }
    }
    __syncthreads();

    if (t < 192) {
      const int l0 = (t >> 3) * 2, d0 = (t & 7) * 4;
      float a0x=0.f,a0y=0.f,a0z=0.f,a0w=0.f, a1x=0.f,a1y=0.f,a1z=0.f,a1w=0.f;
      for (int m = 0; m < 96; ++m) {
        float p0 = su.a.Ss[l0 * 97 + m], p1 = su.a.Ss[(l0 + 1) * 97 + m];
        float4 v = *(const float4*)&su.a.Va[m * 36 + d0];
        a0x = fmaf(p0, v.x, a0x); a0y = fmaf(p0, v.y, a0y);
        a0z = fmaf(p0, v.z, a0z); a0w = fmaf(p0, v.w, a0w);
        a1x = fmaf(p1, v.x, a1x); a1y = fmaf(p1, v.y, a1y);
        a1z = fmaf(p1, v.z, a1z); a1w = fmaf(p1, v.w, a1w);
      }
      const float s0 = su.a.rinv[l0], s1 = su.a.rinv[l0 + 1];
      float* ao = ws + OFF_AOA + (size_t)(j1 * 96 + rb * 48 + l0) * 128 + h * 32 + d0;
      float4 o0; o0.x = a0x * s0; o0.y = a0y * s0; o0.z = a0z * s0; o0.w = a0w * s0;
      float4 o1; o1.x = a1x * s1; o1.y = a1y * s1; o1.z = a1z * s1; o1.w = a1w * s1;
      *(float4*)ao = o0;
      *(float4*)(ao + 128) = o1;
    }
  }
}

// ================================================================
// K7a: t1 = mow@ao + mob + x1, weight-stationary.
// 276 blocks x 8 rows. Thread (c, khalf h): 64-float weight frag in
// 16 float4 VGPRs (loaded ONCE); x rows broadcast from LDS; halves
// combined with __shfl_xor(32).
// ================================================================
__global__ __launch_bounds__(256) void k7a_t1(
    const float* __restrict__ mow, const float* __restrict__ mob,
    float* __restrict__ ws)
{
  __shared__ float rows_in[8][132];
  __shared__ float res[8][132];
  const int t  = threadIdx.x;
  const int r0 = blockIdx.x * 8;

  for (int s = t; s < 1024; s += 256) {
    int ri = s >> 7, c = s & 127;
    int r = r0 + ri;
    float aoval, x1v;
    if (r < 768) {
      float num = ws[OFF_AOP + 0*98304 + (size_t)r*128 + c]
                + ws[OFF_AOP + 1*98304 + (size_t)r*128 + c]
                + ws[OFF_AOP + 2*98304 + (size_t)r*128 + c]
                + ws[OFF_AOP + 3*98304 + (size_t)r*128 + c];
      int hh = c >> 5;
      float den = ws[OFF_DEN + 0*3072 + r*4 + hh] + ws[OFF_DEN + 1*3072 + r*4 + hh]
                + ws[OFF_DEN + 2*3072 + r*4 + hh] + ws[OFF_DEN + 3*3072 + r*4 + hh];
      aoval = num / den;
      x1v = ws[OFF_XE + r*128 + c];
    } else {
      int rr = r - 768;
      aoval = ws[OFF_AOA + (size_t)rr*128 + c];
      int jx = rr / 96, l96 = rr % 96;
      int b = l96 >> 1, sa = l96 & 1;
      int ag = sa ? (jx + 1) : jx;
      x1v = ws[OFF_XA + (b*16 + ag)*128 + c];
    }
    rows_in[ri][c] = aoval;
    res[ri][c] = x1v;
  }

  const int c = (t & 31) | ((t >> 6) << 5);   // col 0..127 (wave w -> cols 32w..32w+31)
  const int h = (t >> 5) & 1;                 // k-half
  float4 wreg[16];
  {
    const float4* wp = (const float4*)(mow + c * 128 + h * 64);
    #pragma unroll
    for (int i = 0; i < 16; ++i) wreg[i] = wp[i];
  }
  const float bias = mob[c];
  __syncthreads();

  #pragma unroll
  for (int ri = 0; ri < 8; ++ri) {
    const float* xr = &rows_in[ri][h * 64];
    float ax = 0.f, ay = 0.f, az = 0.f, aw = 0.f;
    #pragma unroll
    for (int i = 0; i < 16; ++i) {
      float4 x = *(const float4*)&xr[i * 4];
      ax = fmaf(x.x, wreg[i].x, ax); ay = fmaf(x.y, wreg[i].y, ay);
      az = fmaf(x.z, wreg[i].z, az); aw = fmaf(x.w, wreg[i].w, aw);
    }
    float acc = (ax + ay) + (az + aw);
    acc += __shfl_xor(acc, 32);   // combine k-halves (t and t^32 share c)
    if (h == 0)
      ws[OFF_T1 + (size_t)(r0 + ri) * 128 + c] = acc + bias + res[ri][c];
  }
}

// ================================================================
// K7b: ctx = relu(roww@t1 + rob) fused with qv = qw.ctx + qb.
// Same weight-stationary structure; ctx never materialized.
// ================================================================
__global__ __launch_bounds__(256) void k7b_ctx_qv(
    const float* __restrict__ roww, const float* __restrict__ robb,
    const float* __restrict__ qw,  const float* __restrict__ qb,
    float* __restrict__ ws)
{
  __shared__ float rows_in[8][132];
  __shared__ float qpart[8][4];
  const int t  = threadIdx.x;
  const int r0 = blockIdx.x * 8;

  for (int s = t; s < 1024; s += 256) {
    int ri = s >> 7, c = s & 127;
    rows_in[ri][c] = ws[OFF_T1 + (size_t)(r0 + ri) * 128 + c];
  }

  const int c = (t & 31) | ((t >> 6) << 5);
  const int h = (t >> 5) & 1;
  float4 wreg[16];
  {
    const float4* wp = (const float4*)(roww + c * 128 + h * 64);
    #pragma unroll
    for (int i = 0; i < 16; ++i) wreg[i] = wp[i];
  }
  const float bias = robb[c];
  const float qwc  = qw[c];
  __syncthreads();

  #pragma unroll
  for (int ri = 0; ri < 8; ++ri) {
    const float* xr = &rows_in[ri][h * 64];
    float ax = 0.f, ay = 0.f, az = 0.f, aw = 0.f;
    #pragma unroll
    for (int i = 0; i < 16; ++i) {
      float4 x = *(const float4*)&xr[i * 4];
      ax = fmaf(x.x, wreg[i].x, ax); ay = fmaf(x.y, wreg[i].y, ay);
      az = fmaf(x.z, wreg[i].z, az); aw = fmaf(x.w, wreg[i].w, aw);
    }
    float acc = (ax + ay) + (az + aw);
    acc += __shfl_xor(acc, 32);
    float ctx = fmaxf(acc + bias, 0.f);
    float p = (h == 0) ? qwc * ctx : 0.f;
    p += __shfl_xor(p, 1);  p += __shfl_xor(p, 2);  p += __shfl_xor(p, 4);
    p += __shfl_xor(p, 8);  p += __shfl_xor(p, 16); p += __shfl_xor(p, 32);
    if ((t & 63) == 0) qpart[ri][t >> 6] = p;
  }
  __syncthreads();

  if (t < 8) {
    float qv = (qpart[t][0] + qpart[t][1]) + (qpart[t][2] + qpart[t][3]) + qb[0];
    int r = r0 + t;
    if (r < 768) ws[OFF_QVE + r] = qv;
    else         ws[OFF_QVA + (r - 768)] = qv;
  }
}

// ================================================================
// K8: q_values[b,i] = qv_e[b,i] + sum_j qv_a
// ================================================================
__global__ __launch_bounds__(256) void k8_final(const float* __restrict__ ws, float* __restrict__ out)
{
  const int idx = blockIdx.x * 256 + threadIdx.x;
  if (idx >= 768) return;
  const int b = idx >> 4, i = idx & 15;
  float acc = ws[OFF_QVE + idx];
  const float* qva = ws + OFF_QVA;
  #pragma unroll
  for (int j = 1; j <= 15; ++j) {
    int s = (i >= j) ? 0 : 1;
    acc += qva[(j - 1) * 96 + b * 2 + s];
  }
  out[OUT_QV + idx] = acc;
}

// ================================================================
extern "C" void kernel_launch(void* const* d_in, const int* in_sizes, int n_in,
                              void* d_out, int out_size, void* d_ws, size_t ws_size,
                              hipStream_t stream)
{
  (void)in_sizes; (void)n_in; (void)out_size;
  if (ws_size < (size_t)WS_FLOATS * 4) return;

  const float* obs = (const float*)d_in[0];
  const float* aw1 = (const float*)d_in[1];
  const float* ab1 = (const float*)d_in[2];
  const float* aw2 = (const float*)d_in[3];
  const float* ab2 = (const float*)d_in[4];
  const float* aw3 = (const float*)d_in[5];
  const float* ab3 = (const float*)d_in[6];
  const float* eow = (const float*)d_in[7];
  const float* eob = (const float*)d_in[8];
  const float* eaw = (const float*)d_in[9];
  const float* eab = (const float*)d_in[10];
  const float* riw = (const float*)d_in[11];
  const float* rib = (const float*)d_in[12];
  const float* roww= (const float*)d_in[13];
  const float* robb= (const float*)d_in[14];
  const float* miw = (const float*)d_in[15];
  const float* mib = (const float*)d_in[16];
  const float* mow = (const float*)d_in[17];
  const float* mob = (const float*)d_in[18];
  const float* qw  = (const float*)d_in[19];
  const float* qb  = (const float*)d_in[20];

  float* out = (float*)d_out;
  float* ws  = (float*)d_ws;

  k12_front<<<dim3(384), dim3(256), 0, stream>>>(obs, aw1, ab1, aw2, ab2, aw3, ab3,
                                                 eow, eob, eaw, eab, riw, rib, miw, mib,
                                                 out, ws);
  k356_attn<<<dim3(888), dim3(256), 0, stream>>>(ws);
  k7a_t1<<<dim3(276), dim3(256), 0, stream>>>(mow, mob, ws);
  k7b_ctx_qv<<<dim3(276), dim3(256), 0, stream>>>(roww, robb, qw, qb, ws);
  k8_final<<<dim3(3), dim3(256), 0, stream>>>(ws, out);
}

// Round 12
// 190.368 us; speedup vs baseline: 1.1929x; 1.0330x over previous
//
#include <hip/hip_runtime.h>
#include <math.h>

static __device__ __forceinline__ float lrelu(float x){ return x > 0.f ? x : 0.01f * x; }

// ---- workspace layout (float offsets) ----
#define OFF_XE    196608
#define OFF_XA    294912
#define OFF_QKVE  393216
#define OFF_QKVA  688128
#define OFF_AOP   983040    // 4 splits * 768*128
#define OFF_DEN   1376256   // 4 splits * 768*4
#define OFF_AOA   1388544   // 15*96*128
#define OFF_QVE   1572864
#define OFF_QVA   1573632
#define OFF_T1    1575072   // 2208*128 t1 rows
#define WS_FLOATS 1857696

// ---- output layout (fp32 elems) ----
#define OUT_POL 0
#define OUT_QV  24576
#define OUT_EO  25344

#define SCALE_ATTN 0.17677669529663689f  // 1/sqrt(32)

// ================================================================
// K12ws: weight-stationary front end (k7a-proven pattern).
// Blocks 0..191   (E): 4 rows: obs -> eo -> x_e -> qkv_e
// Blocks 192..383 (A): 4 rows: obs -> L1 -> L2 -> L3/pol -> ea -> x_a -> qkv_a
// Thread (c = (t&31)|((t>>6)<<5) in 0..127, h = (t>>5)&1 = k-half).
// Weight frag (16-20 float4) in VGPRs, loaded once per phase; x rows
// read from LDS as wave-broadcast; halves combined via __shfl_xor(32).
// ================================================================
__global__ __launch_bounds__(256) void k12ws_front(
    const float* __restrict__ obs,
    const float* __restrict__ aw1, const float* __restrict__ ab1,
    const float* __restrict__ aw2, const float* __restrict__ ab2,
    const float* __restrict__ aw3, const float* __restrict__ ab3,
    const float* __restrict__ eow, const float* __restrict__ eob,
    const float* __restrict__ eaw, const float* __restrict__ eab,
    const float* __restrict__ riw, const float* __restrict__ rib,
    const float* __restrict__ miw, const float* __restrict__ mib,
    float* __restrict__ out, float* __restrict__ ws)
{
  __shared__ float sA[4][256];   // A: h1, then ea-result in [0..128)  | E: eo
  __shared__ float sB[4][160];   // A: [obs | pol] concat              | E: obs
  __shared__ float sC[4][128];   // A: h2, then x_a                    | E: x_e
  const int t  = threadIdx.x;
  const int bx = blockIdx.x;
  const bool isE = (bx < 192);
  const int r0 = (isE ? bx : bx - 192) * 4;

  const int c = (t & 31) | ((t >> 6) << 5);   // out-col 0..127
  const int h = (t >> 5) & 1;                 // k-half

  // stage obs rows (4 x 128)
  for (int s = t; s < 512; s += 256) {
    int ri = s >> 7, k = s & 127;
    sB[ri][k] = obs[(r0 + ri) * 128 + k];
  }
  __syncthreads();

  if (isE) {
    // ---- phase eo: sB(0..128) -> sA, + out ----
    {
      const float4* wp = (const float4*)(eow + c * 128 + h * 64);
      float4 wf[16];
      #pragma unroll
      for (int i = 0; i < 16; ++i) wf[i] = wp[i];
      const float bias = eob[c];
      #pragma unroll
      for (int r = 0; r < 4; ++r) {
        const float* xr = &sB[r][h * 64];
        float ax = 0.f, ay = 0.f, az = 0.f, aw = 0.f;
        #pragma unroll
        for (int i = 0; i < 16; ++i) {
          float4 x = *(const float4*)&xr[i * 4];
          ax = fmaf(x.x, wf[i].x, ax); ay = fmaf(x.y, wf[i].y, ay);
          az = fmaf(x.z, wf[i].z, az); aw = fmaf(x.w, wf[i].w, aw);
        }
        float acc = (ax + ay) + (az + aw);
        acc += __shfl_xor(acc, 32);
        if (h == 0) {
          float v = acc + bias;
          sA[r][c] = v;
          out[OUT_EO + (r0 + r) * 128 + c] = v;
        }
      }
    }
    __syncthreads();
    // ---- phase x_e: sA -> sC, + ws.XE ----
    {
      const float4* wp = (const float4*)(riw + c * 128 + h * 64);
      float4 wf[16];
      #pragma unroll
      for (int i = 0; i < 16; ++i) wf[i] = wp[i];
      const float bias = rib[c];
      #pragma unroll
      for (int r = 0; r < 4; ++r) {
        const float* xr = &sA[r][h * 64];
        float ax = 0.f, ay = 0.f, az = 0.f, aw = 0.f;
        #pragma unroll
        for (int i = 0; i < 16; ++i) {
          float4 x = *(const float4*)&xr[i * 4];
          ax = fmaf(x.x, wf[i].x, ax); ay = fmaf(x.y, wf[i].y, ay);
          az = fmaf(x.z, wf[i].z, az); aw = fmaf(x.w, wf[i].w, aw);
        }
        float acc = (ax + ay) + (az + aw);
        acc += __shfl_xor(acc, 32);
        if (h == 0) {
          float v = fmaxf(acc + bias, 0.f);
          sC[r][c] = v;
          ws[OFF_XE + (r0 + r) * 128 + c] = v;
        }
      }
    }
    __syncthreads();
    // ---- phase qkv_e: sC -> ws.QKVE (3 col-groups) ----
    #pragma unroll
    for (int g = 0; g < 3; ++g) {
      const float4* wp = (const float4*)(miw + (size_t)(g * 128 + c) * 128 + h * 64);
      float4 wf[16];
      #pragma unroll
      for (int i = 0; i < 16; ++i) wf[i] = wp[i];
      const float bias = mib[g * 128 + c];
      #pragma unroll
      for (int r = 0; r < 4; ++r) {
        const float* xr = &sC[r][h * 64];
        float ax = 0.f, ay = 0.f, az = 0.f, aw = 0.f;
        #pragma unroll
        for (int i = 0; i < 16; ++i) {
          float4 x = *(const float4*)&xr[i * 4];
          ax = fmaf(x.x, wf[i].x, ax); ay = fmaf(x.y, wf[i].y, ay);
          az = fmaf(x.z, wf[i].z, az); aw = fmaf(x.w, wf[i].w, aw);
        }
        float acc = (ax + ay) + (az + aw);
        acc += __shfl_xor(acc, 32);
        if (h == 0)
          ws[OFF_QKVE + (size_t)(r0 + r) * 384 + g * 128 + c] = acc + bias;
      }
    }
  } else {
    // ---- phase L1: sB(0..128) -> sA[.][0..256) (2 col-groups) ----
    #pragma unroll
    for (int g = 0; g < 2; ++g) {
      const float4* wp = (const float4*)(aw1 + (size_t)(g * 128 + c) * 128 + h * 64);
      float4 wf[16];
      #pragma unroll
      for (int i = 0; i < 16; ++i) wf[i] = wp[i];
      const float bias = ab1[g * 128 + c];
      #pragma unroll
      for (int r = 0; r < 4; ++r) {
        const float* xr = &sB[r][h * 64];
        float ax = 0.f, ay = 0.f, az = 0.f, aw = 0.f;
        #pragma unroll
        for (int i = 0; i < 16; ++i) {
          float4 x = *(const float4*)&xr[i * 4];
          ax = fmaf(x.x, wf[i].x, ax); ay = fmaf(x.y, wf[i].y, ay);
          az = fmaf(x.z, wf[i].z, az); aw = fmaf(x.w, wf[i].w, aw);
        }
        float acc = (ax + ay) + (az + aw);
        acc += __shfl_xor(acc, 32);
        if (h == 0) sA[r][g * 128 + c] = lrelu(acc + bias);
      }
    }
    __syncthreads();
    // ---- phase L2: K=256, two frag rounds; sA -> sC ----
    {
      float accs[4];
      {
        const float4* wp = (const float4*)(aw2 + (size_t)c * 256 + h * 64);
        float4 wf[16];
        #pragma unroll
        for (int i = 0; i < 16; ++i) wf[i] = wp[i];
        #pragma unroll
        for (int r = 0; r < 4; ++r) {
          const float* xr = &sA[r][h * 64];
          float ax = 0.f, ay = 0.f, az = 0.f, aw = 0.f;
          #pragma unroll
          for (int i = 0; i < 16; ++i) {
            float4 x = *(const float4*)&xr[i * 4];
            ax = fmaf(x.x, wf[i].x, ax); ay = fmaf(x.y, wf[i].y, ay);
            az = fmaf(x.z, wf[i].z, az); aw = fmaf(x.w, wf[i].w, aw);
          }
          accs[r] = (ax + ay) + (az + aw);
        }
      }
      {
        const float4* wp = (const float4*)(aw2 + (size_t)c * 256 + 128 + h * 64);
        float4 wf[16];
        #pragma unroll
        for (int i = 0; i < 16; ++i) wf[i] = wp[i];
        #pragma unroll
        for (int r = 0; r < 4; ++r) {
          const float* xr = &sA[r][128 + h * 64];
          float ax = 0.f, ay = 0.f, az = 0.f, aw = 0.f;
          #pragma unroll
          for (int i = 0; i < 16; ++i) {
            float4 x = *(const float4*)&xr[i * 4];
            ax = fmaf(x.x, wf[i].x, ax); ay = fmaf(x.y, wf[i].y, ay);
            az = fmaf(x.z, wf[i].z, az); aw = fmaf(x.w, wf[i].w, aw);
          }
          accs[r] += (ax + ay) + (az + aw);
        }
      }
      const float bias = ab2[c];
      #pragma unroll
      for (int r = 0; r < 4; ++r) {
        float acc = accs[r];
        acc += __shfl_xor(acc, 32);
        if (h == 0) sC[r][c] = lrelu(acc + bias);
      }
    }
    __syncthreads();
    // ---- phase L3 + GELU: 32 outs (wave 0 only); sC -> pol in sB[.][128..160) ----
    if (t < 64) {
      const int c2 = t & 31, h2 = t >> 5;
      const float4* wp = (const float4*)(aw3 + (size_t)c2 * 128 + h2 * 64);
      float4 wf[16];
      #pragma unroll
      for (int i = 0; i < 16; ++i) wf[i] = wp[i];
      const float bias = ab3[c2];
      #pragma unroll
      for (int r = 0; r < 4; ++r) {
        const float* xr = &sC[r][h2 * 64];
        float ax = 0.f, ay = 0.f, az = 0.f, aw = 0.f;
        #pragma unroll
        for (int i = 0; i < 16; ++i) {
          float4 x = *(const float4*)&xr[i * 4];
          ax = fmaf(x.x, wf[i].x, ax); ay = fmaf(x.y, wf[i].y, ay);
          az = fmaf(x.z, wf[i].z, az); aw = fmaf(x.w, wf[i].w, aw);
        }
        float acc = (ax + ay) + (az + aw);
        acc += __shfl_xor(acc, 32);
        if (h2 == 0) {
          float a = acc + bias;
          float g = 0.5f * a * (1.f + erff(a * 0.70710678118654752f));
          sB[r][128 + c2] = g;
          out[OUT_POL + (r0 + r) * 32 + c2] = g;
        }
      }
    }
    __syncthreads();
    // ---- phase ea: K=160 (h-halves of 80); sB(160) -> sA[.][0..128) ----
    {
      const float4* wp = (const float4*)(eaw + (size_t)c * 160 + h * 80);
      float4 wf[20];
      #pragma unroll
      for (int i = 0; i < 20; ++i) wf[i] = wp[i];
      const float bias = eab[c];
      #pragma unroll
      for (int r = 0; r < 4; ++r) {
        const float* xr = &sB[r][h * 80];
        float ax = 0.f, ay = 0.f, az = 0.f, aw = 0.f;
        #pragma unroll
        for (int i = 0; i < 20; ++i) {
          float4 x = *(const float4*)&xr[i * 4];
          ax = fmaf(x.x, wf[i].x, ax); ay = fmaf(x.y, wf[i].y, ay);
          az = fmaf(x.z, wf[i].z, az); aw = fmaf(x.w, wf[i].w, aw);
        }
        float acc = (ax + ay) + (az + aw);
        acc += __shfl_xor(acc, 32);
        if (h == 0) sA[r][c] = acc + bias;
      }
    }
    __syncthreads();
    // ---- phase x_a: sA -> sC, + ws.XA ----
    {
      const float4* wp = (const float4*)(riw + c * 128 + h * 64);
      float4 wf[16];
      #pragma unroll
      for (int i = 0; i < 16; ++i) wf[i] = wp[i];
      const float bias = rib[c];
      #pragma unroll
      for (int r = 0; r < 4; ++r) {
        const float* xr = &sA[r][h * 64];
        float ax = 0.f, ay = 0.f, az = 0.f, aw = 0.f;
        #pragma unroll
        for (int i = 0; i < 16; ++i) {
          float4 x = *(const float4*)&xr[i * 4];
          ax = fmaf(x.x, wf[i].x, ax); ay = fmaf(x.y, wf[i].y, ay);
          az = fmaf(x.z, wf[i].z, az); aw = fmaf(x.w, wf[i].w, aw);
        }
        float acc = (ax + ay) + (az + aw);
        acc += __shfl_xor(acc, 32);
        if (h == 0) {
          float v = fmaxf(acc + bias, 0.f);
          sC[r][c] = v;
          ws[OFF_XA + (r0 + r) * 128 + c] = v;
        }
      }
    }
    __syncthreads();
    // ---- phase qkv_a: sC -> ws.QKVA ----
    #pragma unroll
    for (int g = 0; g < 3; ++g) {
      const float4* wp = (const float4*)(miw + (size_t)(g * 128 + c) * 128 + h * 64);
      float4 wf[16];
      #pragma unroll
      for (int i = 0; i < 16; ++i) wf[i] = wp[i];
      const float bias = mib[g * 128 + c];
      #pragma unroll
      for (int r = 0; r < 4; ++r) {
        const float* xr = &sC[r][h * 64];
        float ax = 0.f, ay = 0.f, az = 0.f, aw = 0.f;
        #pragma unroll
        for (int i = 0; i < 16; ++i) {
          float4 x = *(const float4*)&xr[i * 4];
          ax = fmaf(x.x, wf[i].x, ax); ay = fmaf(x.y, wf[i].y, ay);
          az = fmaf(x.z, wf[i].z, az); aw = fmaf(x.w, wf[i].w, aw);
        }
        float acc = (ax + ay) + (az + aw);
        acc += __shfl_xor(acc, 32);
        if (h == 0)
          ws[OFF_QKVA + (size_t)(r0 + r) * 384 + g * 128 + c] = acc + bias;
      }
    }
  }
}

// ================================================================
// K356: fused attention (unchanged).
// ================================================================
__global__ __launch_bounds__(256) void k356_attn(float* __restrict__ ws)
{
  __shared__ __align__(16) union {
    struct { float Qs[16 * 36]; float KsT[32 * 68]; float VsT[32 * 68]; float Ss[16 * 68]; } e;
    struct { float Qb[48 * 33]; float Ka[96 * 33]; float Va[96 * 36]; float Ss[48 * 97]; float rinv[48]; } a;
  } su;
  const int t  = threadIdx.x;
  const int bx = blockIdx.x;

  if (bx < 768) {
    const int l0 = (bx % 48) * 16, h = (bx / 48) & 3, sp = bx / 192;
    const float* qkve = ws + OFF_QKVE;

    for (int f = t; f < 512; f += 256)
      su.e.Qs[(f >> 5) * 36 + (f & 31)] = qkve[(size_t)(l0 + (f >> 5)) * 384 + h * 32 + (f & 31)];
    __syncthreads();

    const int l = t >> 4, j = t & 15, c0 = j * 4;
    float q[32];
    #pragma unroll
    for (int dd = 0; dd < 8; ++dd) {
      float4 qq = *(const float4*)&su.e.Qs[l * 36 + dd * 4];
      q[dd*4+0] = qq.x; q[dd*4+1] = qq.y; q[dd*4+2] = qq.z; q[dd*4+3] = qq.w;
    }
    float o0 = 0.f, o1 = 0.f, dsum = 0.f;

    for (int mt = sp * 3; mt < sp * 3 + 3; ++mt) {
      const int m0 = mt * 64;
      __syncthreads();
      for (int f = t; f < 2048; f += 256) {
        int i = f >> 5, d = f & 31;
        const float* src = qkve + (size_t)(m0 + i) * 384 + h * 32 + d;
        su.e.KsT[d * 68 + i] = src[128];
        su.e.VsT[d * 68 + i] = src[256];
      }
      __syncthreads();

      float s0 = 0.f, s1 = 0.f, s2 = 0.f, s3 = 0.f;
      #pragma unroll
      for (int d = 0; d < 32; ++d) {
        float4 kk = *(const float4*)&su.e.KsT[d * 68 + c0];
        s0 = fmaf(q[d], kk.x, s0); s1 = fmaf(q[d], kk.y, s1);
        s2 = fmaf(q[d], kk.z, s2); s3 = fmaf(q[d], kk.w, s3);
      }
      s0 = expf(s0 * SCALE_ATTN); s1 = expf(s1 * SCALE_ATTN);
      s2 = expf(s2 * SCALE_ATTN); s3 = expf(s3 * SCALE_ATTN);
      float4 sv; sv.x = s0; sv.y = s1; sv.z = s2; sv.w = s3;
      *(float4*)&su.e.Ss[l * 68 + c0] = sv;
      float psum = (s0 + s1) + (s2 + s3);
      psum += __shfl_xor(psum, 1); psum += __shfl_xor(psum, 2);
      psum += __shfl_xor(psum, 4); psum += __shfl_xor(psum, 8);
      dsum += psum;

      float t0x=0.f,t0y=0.f,t0z=0.f,t0w=0.f, t1x=0.f,t1y=0.f,t1z=0.f,t1w=0.f;
      #pragma unroll
      for (int k4 = 0; k4 < 16; ++k4) {
        float4 p  = *(const float4*)&su.e.Ss[l * 68 + k4 * 4];
        float4 va = *(const float4*)&su.e.VsT[j * 68 + k4 * 4];
        float4 vb = *(const float4*)&su.e.VsT[(j + 16) * 68 + k4 * 4];
        t0x = fmaf(p.x, va.x, t0x); t0y = fmaf(p.y, va.y, t0y);
        t0z = fmaf(p.z, va.z, t0z); t0w = fmaf(p.w, va.w, t0w);
        t1x = fmaf(p.x, vb.x, t1x); t1y = fmaf(p.y, vb.y, t1y);
        t1z = fmaf(p.z, vb.z, t1z); t1w = fmaf(p.w, vb.w, t1w);
      }
      o0 += (t0x + t0y) + (t0z + t0w);
      o1 += (t1x + t1y) + (t1z + t1w);
    }

    float* aop = ws + OFF_AOP + (size_t)sp * 98304;
    aop[(size_t)(l0 + l) * 128 + h * 32 + j]      = o0;
    aop[(size_t)(l0 + l) * 128 + h * 32 + j + 16] = o1;
    if (j == 0) ws[OFF_DEN + sp * 3072 + (l0 + l) * 4 + h] = dsum;
  } else {
    const int z  = bx - 768;
    const int j1 = z >> 3;
    const int h  = (z & 7) >> 1, rb = z & 1;
    const int jj = j1 + 1;
    const float* qkva = ws + OFF_QKVA;

    for (int f = t; f < 3072; f += 256) {
      int ml = f >> 5, d = f & 31;
      int bp = ml >> 1, spar = ml & 1;
      int ag = spar ? jj : (jj - 1);
      const float* src = qkva + (size_t)(bp * 16 + ag) * 384 + h * 32 + d;
      su.a.Ka[ml * 33 + d] = src[128];
      su.a.Va[ml * 36 + d] = src[256];
    }
    for (int f = t; f < 1536; f += 256) {
      int ql = f >> 5, d = f & 31;
      int Lb = rb * 48 + ql;
      int b = Lb >> 1, s = Lb & 1;
      int ag = s ? jj : (jj - 1);
      su.a.Qb[ql * 33 + d] = qkva[(size_t)(b * 16 + ag) * 384 + h * 32 + d];
    }
    __syncthreads();

    {
      const int tl = (t >> 4) * 3, tm = (t & 15) * 6;
      float acc[3][6] = {{0.f}};
      #pragma unroll
      for (int d = 0; d < 32; ++d) {
        float qv[3], kv[6];
        #pragma unroll
        for (int r = 0; r < 3; ++r) qv[r] = su.a.Qb[(tl + r) * 33 + d];
        #pragma unroll
        for (int c = 0; c < 6; ++c) kv[c] = su.a.Ka[(tm + c) * 33 + d];
        #pragma unroll
        for (int r = 0; r < 3; ++r)
          #pragma unroll
          for (int c = 0; c < 6; ++c) acc[r][c] = fmaf(qv[r], kv[c], acc[r][c]);
      }
      const float wj = (float)jj, wnj = (float)(16 - jj);
      float rs[3] = {0.f, 0.f, 0.f};
      #pragma unroll
      for (int r = 0; r < 3; ++r)
        #pragma unroll
        for (int c = 0; c < 6; ++c) {
          float w = ((tm + c) & 1) ? wj : wnj;
          float p = w * expf(acc[r][c] * SCALE_ATTN);
          su.a.Ss[(tl + r) * 97 + tm + c] = p;
          rs[r] += p;
        }
      #pragma unroll
      for (int r = 0; r < 3; ++r) {
        rs[r] += __shfl_xor(rs[r], 1); rs[r] += __shfl_xor(rs[r], 2);
        rs[r] += __shfl_xor(rs[r], 4); rs[r] += __shfl_xor(rs[r], 8);
      }
      if ((t & 15) == 0) {
        su.a.rinv[tl + 0] = 1.f / rs[0];
        su.a.rinv[tl + 1] = 1.f / rs[1];
        su.a.rinv[tl + 2] = 1.f / rs[2];
      }
    }
    __syncthreads();

    if (t < 192) {
      const int l0 = (t >> 3) * 2, d0 = (t & 7) * 4;
      float a0x=0.f,a0y=0.f,a0z=0.f,a0w=0.f, a1x=0.f,a1y=0.f,a1z=0.f,a1w=0.f;
      for (int m = 0; m < 96; ++m) {
        float p0 = su.a.Ss[l0 * 97 + m], p1 = su.a.Ss[(l0 + 1) * 97 + m];
        float4 v = *(const float4*)&su.a.Va[m * 36 + d0];
        a0x = fmaf(p0, v.x, a0x); a0y = fmaf(p0, v.y, a0y);
        a0z = fmaf(p0, v.z, a0z); a0w = fmaf(p0, v.w, a0w);
        a1x = fmaf(p1, v.x, a1x); a1y = fmaf(p1, v.y, a1y);
        a1z = fmaf(p1, v.z, a1z); a1w = fmaf(p1, v.w, a1w);
      }
      const float s0 = su.a.rinv[l0], s1 = su.a.rinv[l0 + 1];
      float* ao = ws + OFF_AOA + (size_t)(j1 * 96 + rb * 48 + l0) * 128 + h * 32 + d0;
      float4 o0; o0.x = a0x * s0; o0.y = a0y * s0; o0.z = a0z * s0; o0.w = a0w * s0;
      float4 o1; o1.x = a1x * s1; o1.y = a1y * s1; o1.z = a1z * s1; o1.w = a1w * s1;
      *(float4*)ao = o0;
      *(float4*)(ao + 128) = o1;
    }
  }
}

// ================================================================
// K7a: t1 = mow@ao + mob + x1, weight-stationary. (unchanged)
// ================================================================
__global__ __launch_bounds__(256) void k7a_t1(
    const float* __restrict__ mow, const float* __restrict__ mob,
    float* __restrict__ ws)
{
  __shared__ float rows_in[8][132];
  __shared__ float res[8][132];
  const int t  = threadIdx.x;
  const int r0 = blockIdx.x * 8;

  for (int s = t; s < 1024; s += 256) {
    int ri = s >> 7, c = s & 127;
    int r = r0 + ri;
    float aoval, x1v;
    if (r < 768) {
      float num = ws[OFF_AOP + 0*98304 + (size_t)r*128 + c]
                + ws[OFF_AOP + 1*98304 + (size_t)r*128 + c]
                + ws[OFF_AOP + 2*98304 + (size_t)r*128 + c]
                + ws[OFF_AOP + 3*98304 + (size_t)r*128 + c];
      int hh = c >> 5;
      float den = ws[OFF_DEN + 0*3072 + r*4 + hh] + ws[OFF_DEN + 1*3072 + r*4 + hh]
                + ws[OFF_DEN + 2*3072 + r*4 + hh] + ws[OFF_DEN + 3*3072 + r*4 + hh];
      aoval = num / den;
      x1v = ws[OFF_XE + r*128 + c];
    } else {
      int rr = r - 768;
      aoval = ws[OFF_AOA + (size_t)rr*128 + c];
      int jx = rr / 96, l96 = rr % 96;
      int b = l96 >> 1, sa = l96 & 1;
      int ag = sa ? (jx + 1) : jx;
      x1v = ws[OFF_XA + (b*16 + ag)*128 + c];
    }
    rows_in[ri][c] = aoval;
    res[ri][c] = x1v;
  }

  const int c = (t & 31) | ((t >> 6) << 5);
  const int h = (t >> 5) & 1;
  float4 wreg[16];
  {
    const float4* wp = (const float4*)(mow + c * 128 + h * 64);
    #pragma unroll
    for (int i = 0; i < 16; ++i) wreg[i] = wp[i];
  }
  const float bias = mob[c];
  __syncthreads();

  #pragma unroll
  for (int ri = 0; ri < 8; ++ri) {
    const float* xr = &rows_in[ri][h * 64];
    float ax = 0.f, ay = 0.f, az = 0.f, aw = 0.f;
    #pragma unroll
    for (int i = 0; i < 16; ++i) {
      float4 x = *(const float4*)&xr[i * 4];
      ax = fmaf(x.x, wreg[i].x, ax); ay = fmaf(x.y, wreg[i].y, ay);
      az = fmaf(x.z, wreg[i].z, az); aw = fmaf(x.w, wreg[i].w, aw);
    }
    float acc = (ax + ay) + (az + aw);
    acc += __shfl_xor(acc, 32);
    if (h == 0)
      ws[OFF_T1 + (size_t)(r0 + ri) * 128 + c] = acc + bias + res[ri][c];
  }
}

// ================================================================
// K7b: ctx = relu(roww@t1 + rob) fused with qv = qw.ctx + qb. (unchanged)
// ================================================================
__global__ __launch_bounds__(256) void k7b_ctx_qv(
    const float* __restrict__ roww, const float* __restrict__ robb,
    const float* __restrict__ qw,  const float* __restrict__ qb,
    float* __restrict__ ws)
{
  __shared__ float rows_in[8][132];
  __shared__ float qpart[8][4];
  const int t  = threadIdx.x;
  const int r0 = blockIdx.x * 8;

  for (int s = t; s < 1024; s += 256) {
    int ri = s >> 7, c = s & 127;
    rows_in[ri][c] = ws[OFF_T1 + (size_t)(r0 + ri) * 128 + c];
  }

  const int c = (t & 31) | ((t >> 6) << 5);
  const int h = (t >> 5) & 1;
  float4 wreg[16];
  {
    const float4* wp = (const float4*)(roww + c * 128 + h * 64);
    #pragma unroll
    for (int i = 0; i < 16; ++i) wreg[i] = wp[i];
  }
  const float bias = robb[c];
  const float qwc  = qw[c];
  __syncthreads();

  #pragma unroll
  for (int ri = 0; ri < 8; ++ri) {
    const float* xr = &rows_in[ri][h * 64];
    float ax = 0.f, ay = 0.f, az = 0.f, aw = 0.f;
    #pragma unroll
    for (int i = 0; i < 16; ++i) {
      float4 x = *(const float4*)&xr[i * 4];
      ax = fmaf(x.x, wreg[i].x, ax); ay = fmaf(x.y, wreg[i].y, ay);
      az = fmaf(x.z, wreg[i].z, az); aw = fmaf(x.w, wreg[i].w, aw);
    }
    float acc = (ax + ay) + (az + aw);
    acc += __shfl_xor(acc, 32);
    float ctx = fmaxf(acc + bias, 0.f);
    float p = (h == 0) ? qwc * ctx : 0.f;
    p += __shfl_xor(p, 1);  p += __shfl_xor(p, 2);  p += __shfl_xor(p, 4);
    p += __shfl_xor(p, 8);  p += __shfl_xor(p, 16); p += __shfl_xor(p, 32);
    if ((t & 63) == 0) qpart[ri][t >> 6] = p;
  }
  __syncthreads();

  if (t < 8) {
    float qv = (qpart[t][0] + qpart[t][1]) + (qpart[t][2] + qpart[t][3]) + qb[0];
    int r = r0 + t;
    if (r < 768) ws[OFF_QVE + r] = qv;
    else         ws[OFF_QVA + (r - 768)] = qv;
  }
}

// ================================================================
// K8: q_values[b,i] = qv_e[b,i] + sum_j qv_a
// ================================================================
__global__ __launch_bounds__(256) void k8_final(const float* __restrict__ ws, float* __restrict__ out)
{
  const int idx = blockIdx.x * 256 + threadIdx.x;
  if (idx >= 768) return;
  const int b = idx >> 4, i = idx & 15;
  float acc = ws[OFF_QVE + idx];
  const float* qva = ws + OFF_QVA;
  #pragma unroll
  for (int j = 1; j <= 15; ++j) {
    int s = (i >= j) ? 0 : 1;
    acc += qva[(j - 1) * 96 + b * 2 + s];
  }
  out[OUT_QV + idx] = acc;
}

// ================================================================
extern "C" void kernel_launch(void* const* d_in, const int* in_sizes, int n_in,
                              void* d_out, int out_size, void* d_ws, size_t ws_size,
                              hipStream_t stream)
{
  (void)in_sizes; (void)n_in; (void)out_size;
  if (ws_size < (size_t)WS_FLOATS * 4) return;

  const float* obs = (const float*)d_in[0];
  const float* aw1 = (const float*)d_in[1];
  const float* ab1 = (const float*)d_in[2];
  const float* aw2 = (const float*)d_in[3];
  const float* ab2 = (const float*)d_in[4];
  const float* aw3 = (const float*)d_in[5];
  const float* ab3 = (const float*)d_in[6];
  const float* eow = (const float*)d_in[7];
  const float* eob = (const float*)d_in[8];
  const float* eaw = (const float*)d_in[9];
  const float* eab = (const float*)d_in[10];
  const float* riw = (const float*)d_in[11];
  const float* rib = (const float*)d_in[12];
  const float* roww= (const float*)d_in[13];
  const float* robb= (const float*)d_in[14];
  const float* miw = (const float*)d_in[15];
  const float* mib = (const float*)d_in[16];
  const float* mow = (const float*)d_in[17];
  const float* mob = (const float*)d_in[18];
  const float* qw  = (const float*)d_in[19];
  const float* qb  = (const float*)d_in[20];

  float* out = (float*)d_out;
  float* ws  = (float*)d_ws;

  k12ws_front<<<dim3(384), dim3(256), 0, stream>>>(obs, aw1, ab1, aw2, ab2, aw3, ab3,
                                                   eow, eob, eaw, eab, riw, rib, miw, mib,
                                                   out, ws);
  k356_attn<<<dim3(888), dim3(256), 0, stream>>>(ws);
  k7a_t1<<<dim3(276), dim3(256), 0, stream>>>(mow, mob, ws);
  k7b_ctx_qv<<<dim3(276), dim3(256), 0, stream>>>(roww, robb, qw, qb, ws);
  k8_final<<<dim3(3), dim3(256), 0, stream>>>(ws, out);
}